// Round 6
// baseline (210.815 us; speedup 1.0000x reference)
//
#include <hip/hip_runtime.h>
#include <math.h>

// R6 ABLATION ROUND.
// probe_kernel: pure streaming read of scores+labels (m13 float4-copy shape,
//   no shuffles/exp/tables) -> measures the read-path ceiling for this data.
// ndcg_main_kernel: R5 verbatim, launched AFTER probe (L3-warm) -> separates
//   latency-bound (gets faster warm) from structurally-capped (stays ~50us).

#define G 128

// ws float layout: [0..127] disc, [128..256] cumdisc, [512..2559] partials,
//                  [4096..528383] probe sink (2 MiB)
__global__ void build_tables_kernel(float* __restrict__ tabs) {
    int t = threadIdx.x;
    if (t < G) {
        tabs[t] = 1.0f / log2f((float)(t + 2));
    }
    if (t <= G) {
        float s = 0.0f;
        for (int p = 1; p <= t; ++p) s += 1.0f / log2f((float)(p + 1));
        tabs[G + t] = s;
    }
}

// Pure-load probe: 2048 blocks x 256 threads, 8 f4 + 8 i4 independent loads
// per thread, rotating accumulators, one write per thread (anti-DCE).
__global__ __launch_bounds__(256) void probe_kernel(
        const float* __restrict__ scores,
        const int*   __restrict__ labels,
        float*       __restrict__ sink,
        int n4) {
    const int idx    = blockIdx.x * 256 + threadIdx.x;
    const int stride = gridDim.x * 256;
    const float4* s4 = (const float4*)scores;
    const int4*   l4 = (const int4*)labels;
    float a0 = 0.f, a1 = 0.f, a2 = 0.f, a3 = 0.f;
    int   c0 = 0,   c1 = 0;
#pragma unroll
    for (int k = 0; k < 8; ++k) {
        const int i = idx + k * stride;
        if (i < n4) {
            const float4 x = s4[i];
            const int4   y = l4[i];
            switch (k & 3) {
                case 0: a0 += (x.x + x.y) + (x.z + x.w); break;
                case 1: a1 += (x.x + x.y) + (x.z + x.w); break;
                case 2: a2 += (x.x + x.y) + (x.z + x.w); break;
                default: a3 += (x.x + x.y) + (x.z + x.w); break;
            }
            if (k & 1) c1 += (y.x + y.y) + (y.z + y.w);
            else       c0 += (y.x + y.y) + (y.z + y.w);
        }
    }
    sink[idx] = (a0 + a1) + (a2 + a3) + (float)(c0 + c1);
}

// ===== R5 main kernel, verbatim =====
__global__ __launch_bounds__(256, 4) void ndcg_main_kernel(
        const float* __restrict__ scores,
        const int*   __restrict__ labels,
        const float* __restrict__ tabs,
        float*       __restrict__ partials,
        int B) {
    const int t    = threadIdx.x;
    const int lane = t & 63;
    const int li   = lane & 15;
    const int gs   = lane >> 4;
    const int wib  = t >> 6;
    const long long wave  = (long long)blockIdx.x * 4 + wib;
    const long long gbase = wave * 16;

    __shared__ float bsum;
    if (t == 0) bsum = 0.0f;
    __syncthreads();

    if (gbase < B) {
        const float4* dv = (const float4*)tabs;
        const float4 dA = dv[li];
        const float4 dB = dv[16 + li];

        float4 sA[4], sB[4];
        int4   lA[4], lB[4];
#pragma unroll
        for (int q = 0; q < 4; ++q) {
            const long long g = gbase + q * 4 + gs;
            const float4* sp = (const float4*)(scores + g * G);
            const int4*   lp = (const int4*)(labels + g * G);
            sA[q] = sp[li];
            sB[q] = sp[16 + li];
            lA[q] = lp[li];
            lB[q] = lp[16 + li];
        }

        float esum[4], num[4], cntf[4];
#pragma unroll
        for (int q = 0; q < 4; ++q) {
            float e0 = __expf(sA[q].x), e1 = __expf(sA[q].y);
            float e2 = __expf(sA[q].z), e3 = __expf(sA[q].w);
            float e4 = __expf(sB[q].x), e5 = __expf(sB[q].y);
            float e6 = __expf(sB[q].z), e7 = __expf(sB[q].w);
            esum[q] = ((e0 + e1) + (e2 + e3)) + ((e4 + e5) + (e6 + e7));
            num[q]  = ((e0 * (lA[q].x ? dA.x : 0.f) + e1 * (lA[q].y ? dA.y : 0.f))
                     + (e2 * (lA[q].z ? dA.z : 0.f) + e3 * (lA[q].w ? dA.w : 0.f)))
                    + ((e4 * (lB[q].x ? dB.x : 0.f) + e5 * (lB[q].y ? dB.y : 0.f))
                     + (e6 * (lB[q].z ? dB.z : 0.f) + e7 * (lB[q].w ? dB.w : 0.f)));
            cntf[q] = (float)((lA[q].x + lA[q].y + lA[q].z + lA[q].w)
                            + (lB[q].x + lB[q].y + lB[q].z + lB[q].w));
        }

#pragma unroll
        for (int m = 1; m <= 8; m <<= 1) {
#pragma unroll
            for (int q = 0; q < 4; ++q) {
                esum[q] += __shfl_xor(esum[q], m, 64);
                num[q]  += __shfl_xor(num[q],  m, 64);
                cntf[q] += __shfl_xor(cntf[q], m, 64);
            }
        }

        if (li == 0) {
            float acc = 0.0f;
#pragma unroll
            for (int q = 0; q < 4; ++q) {
                const int c = (int)cntf[q];
                const float idcg = tabs[G + c];
                acc += (c > 0) ? (1.0f - num[q] / (esum[q] * idcg)) : 0.0f;
            }
            atomicAdd(&bsum, acc);
        }
    }
    __syncthreads();
    if (t == 0) partials[blockIdx.x] = bsum;
}

__global__ void finalize_kernel(const float* __restrict__ partials, int n,
                                float* __restrict__ out, float invB) {
    __shared__ float red[256];
    float a = 0.0f;
    for (int i = threadIdx.x; i < n; i += 256) a += partials[i];
    red[threadIdx.x] = a;
    __syncthreads();
    for (int s = 128; s > 0; s >>= 1) {
        if (threadIdx.x < s) red[threadIdx.x] += red[threadIdx.x + s];
        __syncthreads();
    }
    if (threadIdx.x == 0) out[0] = red[0] * invB;
}

extern "C" void kernel_launch(void* const* d_in, const int* in_sizes, int n_in,
                              void* d_out, int out_size, void* d_ws, size_t ws_size,
                              hipStream_t stream) {
    const float* scores = (const float*)d_in[0];
    const int*   labels = (const int*)d_in[1];

    const int n  = in_sizes[0];       // B * G
    const int B  = n / G;             // 131072
    const int n4 = n / 4;             // float4 count
    const int NB = (B + 15) / 16 / 4; // 2048

    float* tabs     = (float*)d_ws;
    float* partials = tabs + 512;
    float* sink     = tabs + 4096;    // 2048*256 floats

    probe_kernel<<<2048, 256, 0, stream>>>(scores, labels, sink, n4);
    build_tables_kernel<<<1, 256, 0, stream>>>(tabs);
    ndcg_main_kernel<<<NB, 256, 0, stream>>>(scores, labels, tabs, partials, B);
    finalize_kernel<<<1, 256, 0, stream>>>(partials, NB, (float*)d_out,
                                           1.0f / (float)B);
}